// Round 8
// baseline (533.491 us; speedup 1.0000x reference)
//
#include <hip/hip_runtime.h>

typedef _Float16 half8 __attribute__((ext_vector_type(8)));
typedef float floatx4 __attribute__((ext_vector_type(4)));

#define LBF 2304   // Lb == Lf
#define K1  1152
#define LDK2 2304  // worst-case compacted stride (Kc can be up to 2304)

__device__ __forceinline__ void gll16(const _Float16* g, _Float16* l) {
    __builtin_amdgcn_global_load_lds((const __attribute__((address_space(1))) void*)g,
                                     (__attribute__((address_space(3))) void*)l, 16, 0, 0);
}

// decode Kc from signed pos'[2303] (excl-scan encoding: valid->e, masked->-e-1)
__device__ __forceinline__ int dec_kc(int s) { return (s >= 0) ? s + 1 : -s - 1; }

// ---------------- stage: downsampled f,b planes -> compact ds ------------------
__global__ void stage_ds(const float* __restrict__ f, const float* __restrict__ bsrc,
                         float* __restrict__ ds) {
    long flat = (long)blockIdx.x * 256 + threadIdx.x;   // [0, 2*4*128*2304)
    int p = flat % 2304;
    long rest = flat / 2304;
    int c = rest % 128;
    int b = (rest / 128) % 4;
    int t = rest / (128 * 4);
    int pi = p / 48, pj = p % 48;
    const float* src = t ? bsrc : f;
    ds[flat] = src[(((long)b * 128 + c) * 96 + 2 * pi) * 96 + 2 * pj];
}

// ---------------- prep: fp patches from ds (3x3, pad 1) ------------------------
__global__ void prep_fp(const float* __restrict__ ds, _Float16* __restrict__ fp) {
    int k = blockIdx.x * 128 + threadIdx.x;   // [0,1152)
    int p = blockIdx.y;                       // [0,2304)
    int b = blockIdx.z;
    int c = k / 9, r = k % 9, u = r / 3, v = r % 3;
    int pi = p / 48, pj = p % 48;
    int y = pi - 1 + u, x = pj - 1 + v;
    float val = 0.f;
    if ((unsigned)y < 48u && (unsigned)x < 48u)
        val = ds[((long)(b * 128 + c)) * 2304 + y * 48 + x];
    fp[((long)b * LBF + p) * K1 + k] = (_Float16)val;
}

// ---------------- prep: wn normalized background patches from ds ---------------
__global__ void prep_wn(const float* __restrict__ ds, _Float16* __restrict__ wn) {
    int p = blockIdx.x, b = blockIdx.y;
    int tid = threadIdx.x;  // 128 threads, 9 elems each
    int pi = p / 48, pj = p % 48;
    const float* dsb = ds + (long)(4 + b) * 128 * 2304;
    float w[9];
    float ss = 0.f;
#pragma unroll
    for (int t = 0; t < 9; t++) {
        int k = tid + t * 128;
        int c = k / 9, r = k % 9, u = r / 3, v = r % 3;
        int y = pi - 1 + u, x = pj - 1 + v;
        float val = 0.f;
        if ((unsigned)y < 48u && (unsigned)x < 48u)
            val = dsb[(long)c * 2304 + y * 48 + x];
        w[t] = val;
        ss += val * val;
    }
    for (int m = 32; m; m >>= 1) ss += __shfl_xor(ss, m);
    __shared__ float sh[2];
    if ((tid & 63) == 0) sh[tid >> 6] = ss;
    __syncthreads();
    float denom = sqrtf(sh[0] + sh[1] + 0.1152f);  // sum(w^2 + ESC)
    float inv = 1.f / denom;
#pragma unroll
    for (int t = 0; t < 9; t++) {
        int k = tid + t * 128;
        wn[((long)b * LBF + p) * K1 + k] = (_Float16)(w[t] * inv);
    }
}

// ---------------- mask -> signed compaction index pos' -------------------------
__global__ void scan_mm(const float* __restrict__ mask, int* __restrict__ pos) {
    int tid = threadIdx.x;  // 256 threads x 9 p's
    int mmb[9], loc[9]; int s = 0;
#pragma unroll
    for (int t = 0; t < 9; t++) {
        int p = tid * 9 + t;
        int pi = p / 48, pj = p % 48;
        float sm = 0.f;
#pragma unroll
        for (int u = 0; u < 3; u++)
#pragma unroll
            for (int v = 0; v < 3; v++) {
                int y = pi - 1 + u, x = pj - 1 + v;
                if ((unsigned)y < 48u && (unsigned)x < 48u)
                    sm += mask[(8 * y) * 384 + 8 * x];
            }
        int m = (sm == 0.f) ? 1 : 0;
        mmb[t] = m; loc[t] = s; s += m;
    }
    __shared__ int sh[256];
    sh[tid] = s; __syncthreads();
    for (int off = 1; off < 256; off <<= 1) {
        int v = (tid >= off) ? sh[tid - off] : 0;
        __syncthreads();
        sh[tid] += v;
        __syncthreads();
    }
    int excl = sh[tid] - s;
#pragma unroll
    for (int t = 0; t < 9; t++) {
        int e = excl + loc[t];
        pos[tid * 9 + t] = mmb[t] ? e : (-e - 1);
    }
}

// ---------------- prep: compacted Wt + self-pad of [Kc, Kpad) ------------------
__global__ void prep_wtc(const float* __restrict__ bsrc, const int* __restrict__ pos,
                         _Float16* __restrict__ wtc) {
    int p = blockIdx.x * 256 + threadIdx.x;   // [0,2304)
    int n = blockIdx.y;                       // [0,2048)
    int b = blockIdx.z;
    int sp = pos[p];
    if (sp < 0) {
        int kc = dec_kc(pos[2303]);
        int kp = (kc + 63) & ~63;
        int mo = p + sp + 1;                  // masked ordinal
        if (mo < kp - kc)
            wtc[((long)b * 2048 + n) * LDK2 + kc + mo] = (_Float16)0.f;
        return;
    }
    int c = n >> 4, u = (n >> 2) & 3, v = n & 3;
    int pi = p / 48, pj = p % 48;
    int y = 2 * pi - 1 + u, x = 2 * pj - 1 + v;
    float val = 0.f;
    if ((unsigned)y < 96u && (unsigned)x < 96u)
        val = bsrc[(((long)b * 128 + c) * 96 + y) * 96 + x];
    wtc[((long)b * 2048 + n) * LDK2 + sp] = (_Float16)val;
}

// ---------------- NT GEMM: 128x64 tiles, BK=32, 3-stage pipeline --------------
// Manual s_waitcnt vmcnt(3) + s_barrier: only the OLDEST tile's loads are
// drained; the two younger prefetch tiles stay in flight across the barrier
// (AITER-style "never vmcnt(0)"). Tile t+2 issued at iter t -> 2-iter aging.
// XOR swizzle phys_chunk = q ^ ((row>>1)&3): staging + ds_read both 2-way (free).
#define GITER(t_, S0, S2)                                                      \
    {                                                                          \
        __asm__ __volatile__("" ::: "memory");                                 \
        if ((t_) + 1 < T) __builtin_amdgcn_s_waitcnt(0xF73); /* vmcnt(3) */    \
        else              __builtin_amdgcn_s_waitcnt(0xF70); /* vmcnt(0) */    \
        __builtin_amdgcn_s_barrier();                                          \
        __asm__ __volatile__("" ::: "memory");                                 \
        if ((t_) + 2 < T) {                                                    \
            int ko = ((t_) + 2) * 32;                                          \
            gll16(gA0 + ko, &smem[S2][dA0]);                                   \
            gll16(gA1 + ko, &smem[S2][dA1]);                                   \
            gll16(gB0 + ko, &smem[S2][dB0]);                                   \
        }                                                                      \
        __asm__ __volatile__("" ::: "memory");                                 \
        half8 af[4], bf[2];                                                    \
        _Pragma("unroll")                                                      \
        for (int i = 0; i < 4; i++) af[i] = *(const half8*)&smem[S0][aoff[i]]; \
        _Pragma("unroll")                                                      \
        for (int j = 0; j < 2; j++) bf[j] = *(const half8*)&smem[S0][boff[j]]; \
        _Pragma("unroll")                                                      \
        for (int i = 0; i < 4; i++)                                            \
            _Pragma("unroll")                                                  \
            for (int j = 0; j < 2; j++)                                        \
                acc[i][j] = __builtin_amdgcn_mfma_f32_16x16x32_f16(af[i], bf[j], acc[i][j], 0, 0, 0); \
    }

__global__ __launch_bounds__(256)
void gemm_nt_p(const _Float16* __restrict__ A, const _Float16* __restrict__ B,
               float* __restrict__ C, int M, int N, int ldk, int swapxy,
               const int* __restrict__ Kpos, int Kstat, long sA, long sB, long sC) {
    A += blockIdx.z * sA; B += blockIdx.z * sB; C += blockIdx.z * sC;
    int K;
    if (Kpos) { int kc = dec_kc(Kpos[0]); K = (kc + 63) & ~63; }
    else K = Kstat;
    const int T = K >> 5;                 // BK=32 iters (K mult of 64 -> T >= 2)
    const int tid = threadIdx.x;
    const int lane = tid & 63, wave = tid >> 6;
    const int wr = wave >> 1, wc = wave & 1;
    const int bm = swapxy ? blockIdx.x : blockIdx.y;
    const int bn = swapxy ? blockIdx.y : blockIdx.x;
    const int m0 = bm * 128, n0 = bn * 64;

    __shared__ _Float16 smem[3][6144];    // per stage: A 128x32 @0, B 64x32 @4096

    floatx4 acc[4][2] = {};

    const int lm = lane & 15, q = lane >> 4;

    // staging: lane l -> row l>>2 in its 16-row call, phys chunk l&3 which
    // holds logical chunk (l&3) ^ ((l>>3)&3)  (row>>1 parity, base mult 16)
    const int rl = lane >> 2;
    const int g = ((lane & 3) ^ ((lane >> 3) & 3)) * 8;   // halves offset
    const _Float16* gA0 = A + (long)(m0 + wave * 32 + rl) * ldk + g;
    const _Float16* gA1 = A + (long)(m0 + wave * 32 + 16 + rl) * ldk + g;
    const _Float16* gB0 = B + (long)(n0 + wave * 16 + rl) * ldk + g;
    const int dA0 = (wave * 32) * 32;
    const int dA1 = (wave * 32 + 16) * 32;
    const int dB0 = 4096 + (wave * 16) * 32;

    // fragment read offsets (halves), swizzled
    int aoff[4], boff[2];
#pragma unroll
    for (int i = 0; i < 4; i++) {
        int r = wr * 64 + i * 16 + lm;
        aoff[i] = r * 32 + (q ^ ((r >> 1) & 3)) * 8;
    }
#pragma unroll
    for (int j = 0; j < 2; j++) {
        int r = wc * 32 + j * 16 + lm;
        boff[j] = 4096 + r * 32 + (q ^ ((r >> 1) & 3)) * 8;
    }

    // prologue: stage tiles 0 and 1
    gll16(gA0, &smem[0][dA0]); gll16(gA1, &smem[0][dA1]); gll16(gB0, &smem[0][dB0]);
    gll16(gA0 + 32, &smem[1][dA0]); gll16(gA1 + 32, &smem[1][dA1]); gll16(gB0 + 32, &smem[1][dB0]);

    for (int t = 0; t < T; t += 3) {
        GITER(t, 0, 2)
        if (t + 1 < T) GITER(t + 1, 1, 0)
        if (t + 2 < T) GITER(t + 2, 2, 1)
    }

    // C/D layout: col = lane&15, row = (lane>>4)*4 + reg   [m89-verified]
    const int col = n0 + wc * 32 + lm;
    const int rowq = q * 4;
#pragma unroll
    for (int i = 0; i < 4; i++) {
        int row = m0 + wr * 64 + i * 16 + rowq;
#pragma unroll
        for (int j = 0; j < 2; j++)
#pragma unroll
            for (int r = 0; r < 4; r++)
                C[(long)(row + r) * N + col + j * 16] = acc[i][j][r];
    }
}

// ---------------- fuse pass A: FT1[y][x] = sum_d ST[y+d][x+d] -----------------
__global__ __launch_bounds__(256)
void fuseA(const float* __restrict__ ST, float* __restrict__ FT1) {
    int y = blockIdx.x, bb = blockIdx.y;
    const float* S = ST + (long)bb * LBF * LBF;
    float* F = FT1 + (long)bb * LBF * LBF;
    const float* r0 = S + (long)(y > 0 ? y - 1 : 0) * LBF;
    const float* r1 = S + (long)y * LBF;
    const float* r2 = S + (long)(y < LBF - 1 ? y + 1 : y) * LBF;
    float m0 = (y > 0) ? 1.f : 0.f;
    float m2 = (y < LBF - 1) ? 1.f : 0.f;
    float* o = F + (long)y * LBF;
#pragma unroll
    for (int u = 0; u < 9; u++) {
        int x = threadIdx.x + u * 256;
        float lo = (x > 0) ? m0 * r0[x - 1] : 0.f;
        float hi = (x < LBF - 1) ? m2 * r2[x + 1] : 0.f;
        o[x] = lo + r1[x] + hi;
    }
}

// ---------------- fuse pass B + masked softmax + compaction + self-pad --------
__global__ __launch_bounds__(256)
void fuseB_softmax(const float* __restrict__ FT1, const int* __restrict__ pos,
                   _Float16* __restrict__ attTc_g) {
    int j = blockIdx.x, bb = blockIdx.y;
    int tid = threadIdx.x;
    const float* F = FT1 + (long)bb * LBF * LBF;
    _Float16* orow = attTc_g + ((long)bb * LBF + j) * LDK2;
    int Pj = (j % 48) * 48 + j / 48;
    long roff[3]; bool jok[3];
#pragma unroll
    for (int t = 0; t < 3; t++) {
        int j2 = Pj + t - 1;
        jok[t] = (unsigned)j2 < (unsigned)LBF;
        int jc = jok[t] ? j2 : 0;
        roff[t] = (long)((jc % 48) * 48 + jc / 48) * LBF;
    }
    float v[9]; int ps[9];
    float mx = -1e30f;
#pragma unroll
    for (int u = 0; u < 9; u++) {
        int x = tid + u * 256;
        int sp = pos[x];
        ps[u] = sp;
        float xv = 0.f;
        if (sp >= 0) {
            int a = x / 48, b = x - a * 48;
            int Px = b * 48 + a;
            float acc = 0.f;
#pragma unroll
            for (int t = 0; t < 3; t++) {
                int d2 = t - 1;
                int uu = Px + d2;
                if (jok[t] && (unsigned)uu < (unsigned)LBF) {
                    int ad = a + d2;
                    int c = ((unsigned)ad < 48u) ? (x + 48 * d2)
                          : (ad == 48 ? (b + 1) : (2255 + b));
                    acc += F[roff[t] + c];
                }
            }
            xv = acc * 10.f;
        }
        v[u] = xv;
        mx = fmaxf(mx, xv);
    }
    for (int m = 32; m; m >>= 1) mx = fmaxf(mx, __shfl_xor(mx, m));
    __shared__ float sh[4], sh2[4];
    if ((tid & 63) == 0) sh[tid >> 6] = mx;
    __syncthreads();
    mx = fmaxf(fmaxf(sh[0], sh[1]), fmaxf(sh[2], sh[3]));
    float sum = 0.f;
#pragma unroll
    for (int u = 0; u < 9; u++) { v[u] = __expf(v[u] - mx); sum += v[u]; }
    for (int m = 32; m; m >>= 1) sum += __shfl_xor(sum, m);
    if ((tid & 63) == 0) sh2[tid >> 6] = sum;
    __syncthreads();
    sum = sh2[0] + sh2[1] + sh2[2] + sh2[3];
    float inv = 1.f / sum;
#pragma unroll
    for (int u = 0; u < 9; u++) {
        if (ps[u] >= 0) orow[ps[u]] = (_Float16)(v[u] * inv);
    }
    int kc = dec_kc(pos[2303]);
    int kp = (kc + 63) & ~63;
    if (tid < kp - kc) orow[kc + tid] = (_Float16)0.f;
}

// ---------------- scatter from MT[n][p]: coalesced transposed-conv gather -----
__global__ void scatter_out(const float* __restrict__ MT_, float* __restrict__ out) {
    int yx = blockIdx.x * 256 + threadIdx.x;  // [0, 9216)
    int c = blockIdx.y, b = blockIdx.z;
    int y = yx / 96, x = yx % 96;
    const float* Mb = MT_ + (long)b * 2048 * LBF;
    float s = 0.f;
    for (int uu = (y + 1) & 1; uu < 4; uu += 2) {
        int fi = (y + 1 - uu) >> 1;
        if ((unsigned)fi >= 48u) continue;
        for (int vv = (x + 1) & 1; vv < 4; vv += 2) {
            int fj = (x + 1 - vv) >> 1;
            if ((unsigned)fj >= 48u) continue;
            s += Mb[(long)(c * 16 + uu * 4 + vv) * LBF + fi * 48 + fj];
        }
    }
    out[(((long)b * 128 + c) * 96 + y) * 96 + x] = 0.25f * s;
}

extern "C" void kernel_launch(void* const* d_in, const int* in_sizes, int n_in,
                              void* d_out, int out_size, void* d_ws, size_t ws_size,
                              hipStream_t stream) {
    const float* f    = (const float*)d_in[0];
    const float* bsrc = (const float*)d_in[1];
    const float* mask = (const float*)d_in[2];
    float* out = (float*)d_out;

    char* ws = (char*)d_ws;
    const size_t offR1  = 84934656;
    const size_t offWn  = offR1 + 21233664;
    const size_t offWtc = offR1 + 42467328;
    const size_t offFT1 = offWtc + 37748736;          // 165150720
    const size_t offPos = offFT1 + 2ul * 21233664;    // 207618048
    const size_t NEED   = offPos + 9216;              // 207627264
    if (ws_size < NEED) return;  // visible failure, no OOB writes

    float*    ST    = (float*)(ws + 0);
    float*    MT    = (float*)(ws + 0);
    _Float16* fp    = (_Float16*)(ws + offR1);
    _Float16* wn    = (_Float16*)(ws + offWn);
    _Float16* attTc = (_Float16*)(ws + offR1);
    _Float16* Wtc   = (_Float16*)(ws + offWtc);
    float*    ds    = (float*)(ws + offFT1);
    float*    FT1   = (float*)(ws + offFT1);
    int*      pos   = (int*)(ws + offPos);

    stage_ds<<<dim3(9216), 256, 0, stream>>>(f, bsrc, ds);
    scan_mm<<<dim3(1), 256, 0, stream>>>(mask, pos);
    prep_fp<<<dim3(9, 2304, 4), 128, 0, stream>>>(ds, fp);
    prep_wn<<<dim3(2304, 4), 128, 0, stream>>>(ds, wn);
    prep_wtc<<<dim3(9, 2048, 4), 256, 0, stream>>>(bsrc, pos, Wtc);

    // GEMM1: ST[j,i] = sum_k fp[j,k] * wn[i,k]  (static K=1152); N-tiles fast
    gemm_nt_p<<<dim3(36, 18, 4), 256, 0, stream>>>(fp, wn, ST, 2304, 2304, K1, 0,
        nullptr, K1, (long)2304 * K1, (long)2304 * K1, (long)2304 * 2304);

    for (int g = 0; g < 2; g++) {
        fuseA<<<dim3(LBF, 2), 256, 0, stream>>>(ST + (long)g * 2 * LBF * LBF, FT1);
        fuseB_softmax<<<dim3(LBF, 2), 256, 0, stream>>>(FT1, pos,
            attTc + (long)g * 2 * LBF * LDK2);
    }

    // GEMM2 transposed output, M(Wtc)-tiles fast: MT[n,p] = Wtc . attTc^T
    gemm_nt_p<<<dim3(16, 36, 4), 256, 0, stream>>>(Wtc, attTc, MT, 2048, 2304, LDK2, 1,
        pos + 2303, 0, (long)2048 * LDK2, (long)2304 * LDK2, (long)2048 * 2304);

    scatter_out<<<dim3(36, 128, 4), 256, 0, stream>>>(MT, out);
}

// Round 9
// 461.074 us; speedup vs baseline: 1.1571x; 1.1571x over previous
//
#include <hip/hip_runtime.h>

typedef _Float16 half8 __attribute__((ext_vector_type(8)));
typedef float floatx4 __attribute__((ext_vector_type(4)));

#define LBF 2304   // Lb == Lf
#define K1  1152
#define LDK2 2304  // worst-case compacted stride (Kc can be up to 2304)

__device__ __forceinline__ void gll16(const _Float16* g, _Float16* l) {
    __builtin_amdgcn_global_load_lds((const __attribute__((address_space(1))) void*)g,
                                     (__attribute__((address_space(3))) void*)l, 16, 0, 0);
}

// decode Kc from signed pos'[2303] (excl-scan encoding: valid->e, masked->-e-1)
__device__ __forceinline__ int dec_kc(int s) { return (s >= 0) ? s + 1 : -s - 1; }

// ---------------- stage ds (blocks 0..9215) + mask scan (block 9216) ----------
__global__ void stage_scan(const float* __restrict__ f, const float* __restrict__ bsrc,
                           const float* __restrict__ mask,
                           float* __restrict__ ds, int* __restrict__ pos) {
    int tid = threadIdx.x;
    if (blockIdx.x < 9216) {
        long flat = (long)blockIdx.x * 256 + tid;   // [0, 2*4*128*2304)
        int p = flat % 2304;
        long rest = flat / 2304;
        int c = rest % 128;
        int b = (rest / 128) % 4;
        int t = rest / (128 * 4);
        int pi = p / 48, pj = p % 48;
        const float* src = t ? bsrc : f;
        ds[flat] = src[(((long)b * 128 + c) * 96 + 2 * pi) * 96 + 2 * pj];
        return;
    }
    // ---- scan block: mask -> signed compaction index pos' ----
    int mmb[9], loc[9]; int s = 0;
#pragma unroll
    for (int t = 0; t < 9; t++) {
        int p = tid * 9 + t;
        int pi = p / 48, pj = p % 48;
        float sm = 0.f;
#pragma unroll
        for (int u = 0; u < 3; u++)
#pragma unroll
            for (int v = 0; v < 3; v++) {
                int y = pi - 1 + u, x = pj - 1 + v;
                if ((unsigned)y < 48u && (unsigned)x < 48u)
                    sm += mask[(8 * y) * 384 + 8 * x];
            }
        int m = (sm == 0.f) ? 1 : 0;
        mmb[t] = m; loc[t] = s; s += m;
    }
    __shared__ int sh[256];
    sh[tid] = s; __syncthreads();
    for (int off = 1; off < 256; off <<= 1) {
        int v = (tid >= off) ? sh[tid - off] : 0;
        __syncthreads();
        sh[tid] += v;
        __syncthreads();
    }
    int excl = sh[tid] - s;
#pragma unroll
    for (int t = 0; t < 9; t++) {
        int e = excl + loc[t];
        pos[tid * 9 + t] = mmb[t] ? e : (-e - 1);
    }
}

// ---------------- prep: fp patches from ds (3x3, pad 1) ------------------------
__global__ void prep_fp(const float* __restrict__ ds, _Float16* __restrict__ fp) {
    int k = blockIdx.x * 128 + threadIdx.x;   // [0,1152)
    int p = blockIdx.y;                       // [0,2304)
    int b = blockIdx.z;
    int c = k / 9, r = k % 9, u = r / 3, v = r % 3;
    int pi = p / 48, pj = p % 48;
    int y = pi - 1 + u, x = pj - 1 + v;
    float val = 0.f;
    if ((unsigned)y < 48u && (unsigned)x < 48u)
        val = ds[((long)(b * 128 + c)) * 2304 + y * 48 + x];
    fp[((long)b * LBF + p) * K1 + k] = (_Float16)val;
}

// ---------------- prep: wn normalized background patches from ds ---------------
__global__ void prep_wn(const float* __restrict__ ds, _Float16* __restrict__ wn) {
    int p = blockIdx.x, b = blockIdx.y;
    int tid = threadIdx.x;  // 128 threads, 9 elems each
    int pi = p / 48, pj = p % 48;
    const float* dsb = ds + (long)(4 + b) * 128 * 2304;
    float w[9];
    float ss = 0.f;
#pragma unroll
    for (int t = 0; t < 9; t++) {
        int k = tid + t * 128;
        int c = k / 9, r = k % 9, u = r / 3, v = r % 3;
        int y = pi - 1 + u, x = pj - 1 + v;
        float val = 0.f;
        if ((unsigned)y < 48u && (unsigned)x < 48u)
            val = dsb[(long)c * 2304 + y * 48 + x];
        w[t] = val;
        ss += val * val;
    }
    for (int m = 32; m; m >>= 1) ss += __shfl_xor(ss, m);
    __shared__ float sh[2];
    if ((tid & 63) == 0) sh[tid >> 6] = ss;
    __syncthreads();
    float denom = sqrtf(sh[0] + sh[1] + 0.1152f);  // sum(w^2 + ESC)
    float inv = 1.f / denom;
#pragma unroll
    for (int t = 0; t < 9; t++) {
        int k = tid + t * 128;
        wn[((long)b * LBF + p) * K1 + k] = (_Float16)(w[t] * inv);
    }
}

// ---------------- prep: compacted Wt, line-efficient ---------------------------
// grid (9, 128 c, 4 b): thread owns p for channel c, emits all 16 (u,v) taps.
// Reads each bsrc line once per (c,b) instead of 16x.
__global__ void prep_wtc(const float* __restrict__ bsrc, const int* __restrict__ pos,
                         _Float16* __restrict__ wtc) {
    int p = blockIdx.x * 256 + threadIdx.x;   // [0,2304)
    int c = blockIdx.y;                       // [0,128)
    int b = blockIdx.z;
    int sp = pos[p];
    long base = ((long)b * 2048 + c * 16) * LDK2;
    if (sp < 0) {
        int kc = dec_kc(pos[2303]);
        int kp = (kc + 63) & ~63;
        int mo = p + sp + 1;                  // masked ordinal
        if (mo < kp - kc) {
#pragma unroll
            for (int n = 0; n < 16; n++)
                wtc[base + (long)n * LDK2 + kc + mo] = (_Float16)0.f;
        }
        return;
    }
    int pi = p / 48, pj = p % 48;
    const float* src = bsrc + ((long)b * 128 + c) * 96 * 96;
#pragma unroll
    for (int u = 0; u < 4; u++) {
        int y = 2 * pi - 1 + u;
        bool yok = (unsigned)y < 96u;
#pragma unroll
        for (int v = 0; v < 4; v++) {
            int x = 2 * pj - 1 + v;
            float val = 0.f;
            if (yok && (unsigned)x < 96u) val = src[y * 96 + x];
            wtc[base + (long)(u * 4 + v) * LDK2 + sp] = (_Float16)val;
        }
    }
}

// ---------------- NT GEMM, BK=64, double-buffered LDS (R6 winner) -------------
__device__ __forceinline__ void gemm_compute(const _Float16* lA, const _Float16* lB,
                                             floatx4 (&acc)[4][4],
                                             int wr, int wc, int lm, int pcp) {
    half8 af[4], bf[4];
#pragma unroll
    for (int t = 0; t < 4; t++) {
        af[t] = *(const half8*)&lA[(wr * 64 + t * 16 + lm) * 64 + pcp];
        bf[t] = *(const half8*)&lB[(wc * 64 + t * 16 + lm) * 64 + pcp];
    }
#pragma unroll
    for (int i = 0; i < 4; i++)
#pragma unroll
        for (int j = 0; j < 4; j++)
            acc[i][j] = __builtin_amdgcn_mfma_f32_16x16x32_f16(af[i], bf[j], acc[i][j], 0, 0, 0);
#pragma unroll
    for (int t = 0; t < 4; t++) {
        af[t] = *(const half8*)&lA[(wr * 64 + t * 16 + lm) * 64 + (pcp ^ 32)];
        bf[t] = *(const half8*)&lB[(wc * 64 + t * 16 + lm) * 64 + (pcp ^ 32)];
    }
#pragma unroll
    for (int i = 0; i < 4; i++)
#pragma unroll
        for (int j = 0; j < 4; j++)
            acc[i][j] = __builtin_amdgcn_mfma_f32_16x16x32_f16(af[i], bf[j], acc[i][j], 0, 0, 0);
}

__global__ __launch_bounds__(256)
void gemm_nt64(const _Float16* __restrict__ A, const _Float16* __restrict__ B,
               float* __restrict__ C, int M, int N, int ldk, int swapxy,
               const int* __restrict__ Kpos, int Kstat, long sA, long sB, long sC) {
    A += blockIdx.z * sA; B += blockIdx.z * sB; C += blockIdx.z * sC;
    int K;
    if (Kpos) { int kc = dec_kc(Kpos[0]); K = (kc + 63) & ~63; }
    else K = Kstat;
    const int tid = threadIdx.x;
    const int lane = tid & 63, wave = tid >> 6;
    const int wr = wave >> 1, wc = wave & 1;
    const int bm = swapxy ? blockIdx.x : blockIdx.y;
    const int bn = swapxy ? blockIdx.y : blockIdx.x;
    const int m0 = bm * 128, n0 = bn * 128;

    __shared__ _Float16 sm[4][128 * 64];   // [buf*2 + (A=0/B=1)]: 4 x 16 KB

    floatx4 acc[4][4] = {};

    const int lm = lane & 15, q = lane >> 4;
    const int pcp = (q ^ (lm & 7)) * 8;      // substep-0 phys offset (halves)

    const int srow8 = lane >> 3;
    const int gc = ((lane & 7) ^ srow8) * 8;  // global halves offset (XOR swizzle)
    const _Float16* gA[4]; const _Float16* gB[4];
    int dOff[4];
#pragma unroll
    for (int c = 0; c < 4; c++) {
        int r = (wave * 4 + c) * 8 + srow8;
        gA[c] = A + (long)(m0 + r) * ldk + gc;
        gB[c] = B + (long)(n0 + r) * ldk + gc;
        dOff[c] = (wave * 4 + c) * 512;
    }

    if (K > 0) {
#pragma unroll
        for (int c = 0; c < 4; c++) gll16(gA[c], &sm[0][dOff[c]]);
#pragma unroll
        for (int c = 0; c < 4; c++) gll16(gB[c], &sm[1][dOff[c]]);
        __syncthreads();
        int k0 = 0, buf = 0;
        while (true) {
            int kn = k0 + 64;
            if (kn < K) {
                const int nb = (buf ^ 1) * 2;
#pragma unroll
                for (int c = 0; c < 4; c++) gll16(gA[c] + kn, &sm[nb][dOff[c]]);
#pragma unroll
                for (int c = 0; c < 4; c++) gll16(gB[c] + kn, &sm[nb + 1][dOff[c]]);
            }
            gemm_compute(sm[buf * 2], sm[buf * 2 + 1], acc, wr, wc, lm, pcp);
            __syncthreads();
            k0 = kn; buf ^= 1;
            if (k0 >= K) break;
        }
    }

    // C/D layout: col = lane&15, row = (lane>>4)*4 + reg   [m89-verified]
    const int col = n0 + wc * 64 + lm;
    const int rowq = q * 4;
#pragma unroll
    for (int i = 0; i < 4; i++) {
        int row = m0 + wr * 64 + i * 16 + rowq;
#pragma unroll
        for (int j = 0; j < 4; j++)
#pragma unroll
            for (int r = 0; r < 4; r++)
                C[(long)(row + r) * N + col + j * 16] = acc[i][j][r];
    }
}

// ---------------- fuse pass A: FT1[y][x] = sum_d ST[y+d][x+d] -----------------
__global__ __launch_bounds__(256)
void fuseA(const float* __restrict__ ST, float* __restrict__ FT1) {
    int y = blockIdx.x, bb = blockIdx.y;
    const float* S = ST + (long)bb * LBF * LBF;
    float* F = FT1 + (long)bb * LBF * LBF;
    const float* r0 = S + (long)(y > 0 ? y - 1 : 0) * LBF;
    const float* r1 = S + (long)y * LBF;
    const float* r2 = S + (long)(y < LBF - 1 ? y + 1 : y) * LBF;
    float m0 = (y > 0) ? 1.f : 0.f;
    float m2 = (y < LBF - 1) ? 1.f : 0.f;
    float* o = F + (long)y * LBF;
#pragma unroll
    for (int u = 0; u < 9; u++) {
        int x = threadIdx.x + u * 256;
        float lo = (x > 0) ? m0 * r0[x - 1] : 0.f;
        float hi = (x < LBF - 1) ? m2 * r2[x + 1] : 0.f;
        o[x] = lo + r1[x] + hi;
    }
}

// ---------------- fuse pass B + masked softmax + compaction + self-pad --------
__global__ __launch_bounds__(256)
void fuseB_softmax(const float* __restrict__ FT1, const int* __restrict__ pos,
                   _Float16* __restrict__ attTc_g) {
    int j = blockIdx.x, bb = blockIdx.y;
    int tid = threadIdx.x;
    const float* F = FT1 + (long)bb * LBF * LBF;
    _Float16* orow = attTc_g + ((long)bb * LBF + j) * LDK2;
    int Pj = (j % 48) * 48 + j / 48;
    long roff[3]; bool jok[3];
#pragma unroll
    for (int t = 0; t < 3; t++) {
        int j2 = Pj + t - 1;
        jok[t] = (unsigned)j2 < (unsigned)LBF;
        int jc = jok[t] ? j2 : 0;
        roff[t] = (long)((jc % 48) * 48 + jc / 48) * LBF;
    }
    float v[9]; int ps[9];
    float mx = -1e30f;
#pragma unroll
    for (int u = 0; u < 9; u++) {
        int x = tid + u * 256;
        int sp = pos[x];
        ps[u] = sp;
        float xv = 0.f;
        if (sp >= 0) {
            int a = x / 48, b = x - a * 48;
            int Px = b * 48 + a;
            float acc = 0.f;
#pragma unroll
            for (int t = 0; t < 3; t++) {
                int d2 = t - 1;
                int uu = Px + d2;
                if (jok[t] && (unsigned)uu < (unsigned)LBF) {
                    int ad = a + d2;
                    int c = ((unsigned)ad < 48u) ? (x + 48 * d2)
                          : (ad == 48 ? (b + 1) : (2255 + b));
                    acc += F[roff[t] + c];
                }
            }
            xv = acc * 10.f;
        }
        v[u] = xv;
        mx = fmaxf(mx, xv);
    }
    for (int m = 32; m; m >>= 1) mx = fmaxf(mx, __shfl_xor(mx, m));
    __shared__ float sh[4], sh2[4];
    if ((tid & 63) == 0) sh[tid >> 6] = mx;
    __syncthreads();
    mx = fmaxf(fmaxf(sh[0], sh[1]), fmaxf(sh[2], sh[3]));
    float sum = 0.f;
#pragma unroll
    for (int u = 0; u < 9; u++) { v[u] = __expf(v[u] - mx); sum += v[u]; }
    for (int m = 32; m; m >>= 1) sum += __shfl_xor(sum, m);
    if ((tid & 63) == 0) sh2[tid >> 6] = sum;
    __syncthreads();
    sum = sh2[0] + sh2[1] + sh2[2] + sh2[3];
    float inv = 1.f / sum;
#pragma unroll
    for (int u = 0; u < 9; u++) {
        if (ps[u] >= 0) orow[ps[u]] = (_Float16)(v[u] * inv);
    }
    int kc = dec_kc(pos[2303]);
    int kp = (kc + 63) & ~63;
    if (tid < kp - kc) orow[kc + tid] = (_Float16)0.f;
}

// ---------------- scatter from MT[n][p]: coalesced transposed-conv gather -----
__global__ void scatter_out(const float* __restrict__ MT_, float* __restrict__ out) {
    int yx = blockIdx.x * 256 + threadIdx.x;  // [0, 9216)
    int c = blockIdx.y, b = blockIdx.z;
    int y = yx / 96, x = yx % 96;
    const float* Mb = MT_ + (long)b * 2048 * LBF;
    float s = 0.f;
    for (int uu = (y + 1) & 1; uu < 4; uu += 2) {
        int fi = (y + 1 - uu) >> 1;
        if ((unsigned)fi >= 48u) continue;
        for (int vv = (x + 1) & 1; vv < 4; vv += 2) {
            int fj = (x + 1 - vv) >> 1;
            if ((unsigned)fj >= 48u) continue;
            s += Mb[(long)(c * 16 + uu * 4 + vv) * LBF + fi * 48 + fj];
        }
    }
    out[(((long)b * 128 + c) * 96 + y) * 96 + x] = 0.25f * s;
}

extern "C" void kernel_launch(void* const* d_in, const int* in_sizes, int n_in,
                              void* d_out, int out_size, void* d_ws, size_t ws_size,
                              hipStream_t stream) {
    const float* f    = (const float*)d_in[0];
    const float* bsrc = (const float*)d_in[1];
    const float* mask = (const float*)d_in[2];
    float* out = (float*)d_out;

    char* ws = (char*)d_ws;
    const size_t offR1  = 84934656;
    const size_t offWn  = offR1 + 21233664;
    const size_t offWtc = offR1 + 42467328;
    const size_t offFT1 = offWtc + 37748736;          // 165150720
    const size_t offPos = offFT1 + 2ul * 21233664;    // 207618048
    const size_t NEED   = offPos + 9216;              // 207627264
    if (ws_size < NEED) return;  // visible failure, no OOB writes

    float*    ST    = (float*)(ws + 0);
    float*    MT    = (float*)(ws + 0);
    _Float16* fp    = (_Float16*)(ws + offR1);
    _Float16* wn    = (_Float16*)(ws + offWn);
    _Float16* attTc = (_Float16*)(ws + offR1);
    _Float16* Wtc   = (_Float16*)(ws + offWtc);
    float*    ds    = (float*)(ws + offFT1);
    float*    FT1   = (float*)(ws + offFT1);
    int*      pos   = (int*)(ws + offPos);

    stage_scan<<<dim3(9217), 256, 0, stream>>>(f, bsrc, mask, ds, pos);
    prep_fp<<<dim3(9, 2304, 4), 128, 0, stream>>>(ds, fp);
    prep_wn<<<dim3(2304, 4), 128, 0, stream>>>(ds, wn);
    prep_wtc<<<dim3(9, 128, 4), 256, 0, stream>>>(bsrc, pos, Wtc);

    // GEMM1: ST[j,i] = sum_k fp[j,k] * wn[i,k]  (static K=1152)
    gemm_nt64<<<dim3(18, 18, 4), 256, 0, stream>>>(fp, wn, ST, 2304, 2304, K1, 0,
        nullptr, K1, (long)2304 * K1, (long)2304 * K1, (long)2304 * 2304);

    for (int g = 0; g < 2; g++) {
        fuseA<<<dim3(LBF, 2), 256, 0, stream>>>(ST + (long)g * 2 * LBF * LBF, FT1);
        fuseB_softmax<<<dim3(LBF, 2), 256, 0, stream>>>(FT1, pos,
            attTc + (long)g * 2 * LBF * LDK2);
    }

    // GEMM2 transposed output, R4 block-order: x sweeps Wtc (A), y pins attTc (B)
    gemm_nt64<<<dim3(16, 18, 4), 256, 0, stream>>>(Wtc, attTc, MT, 2048, 2304, LDK2, 1,
        pos + 2303, 0, (long)2048 * LDK2, (long)2304 * LDK2, (long)2048 * 2304);

    scatter_out<<<dim3(36, 128, 4), 256, 0, stream>>>(MT, out);
}